// Round 1
// baseline (1010.458 us; speedup 1.0000x reference)
//
#include <hip/hip_runtime.h>

#define U_N 50000
#define I_N 25000
#define D_N 128
#define N_N (U_N + I_N)

// ---------------- histogram: cnt[src[e]] += 1 ----------------
__global__ __launch_bounds__(256) void hist_kernel(const int* __restrict__ src,
                                                   int* __restrict__ cnt, int E) {
    int i = blockIdx.x * blockDim.x + threadIdx.x;
    int stride = gridDim.x * blockDim.x;
    for (; i < E; i += stride) {
        atomicAdd(&cnt[src[i]], 1);
    }
}

// ---------- single-block exclusive scan + dinv + fill_pos ----------
__global__ __launch_bounds__(256) void scan_kernel(const int* __restrict__ cnt,
                                                   int* __restrict__ row_ptr,
                                                   int* __restrict__ fill_pos,
                                                   float* __restrict__ dinv,
                                                   int N, int E) {
    __shared__ int sdata[256];
    __shared__ int carry_s;
    int t = threadIdx.x;
    if (t == 0) carry_s = 0;
    __syncthreads();
    for (int base = 0; base < N; base += 256) {
        int i = base + t;
        int v = (i < N) ? cnt[i] : 0;
        sdata[t] = v;
        __syncthreads();
        // Hillis-Steele inclusive scan
        for (int off = 1; off < 256; off <<= 1) {
            int add = (t >= off) ? sdata[t - off] : 0;
            __syncthreads();
            sdata[t] += add;
            __syncthreads();
        }
        int incl = sdata[t];
        int carry = carry_s;
        int excl = carry + incl - v;
        if (i < N) {
            row_ptr[i]  = excl;
            fill_pos[i] = excl;
            dinv[i] = (v > 0) ? rsqrtf((float)v) : 0.0f;
        }
        __syncthreads();                  // everyone has read carry_s
        if (t == 255) carry_s = carry + incl;
        __syncthreads();                  // update visible next iter
    }
    if (t == 0) row_ptr[N] = E;
}

// ---------------- scatter edges into CSR order ----------------
__global__ __launch_bounds__(256) void scatter_kernel(const int* __restrict__ src,
                                                      const int* __restrict__ dst,
                                                      int* __restrict__ fill_pos,
                                                      const float* __restrict__ dinv,
                                                      int* __restrict__ csr_dst,
                                                      float* __restrict__ csr_w, int E) {
    int i = blockIdx.x * blockDim.x + threadIdx.x;
    int stride = gridDim.x * blockDim.x;
    for (; i < E; i += stride) {
        int s = src[i];
        int d = dst[i];
        int pos = atomicAdd(&fill_pos[s], 1);
        csr_dst[pos] = d;
        csr_w[pos] = dinv[s] * dinv[d];
    }
}

// ------------- init: x0 = concat(ue, ie); avg = 0.25*x0 -------------
__global__ __launch_bounds__(256) void init_kernel(const float4* __restrict__ ue,
                                                   const float4* __restrict__ ie,
                                                   float4* __restrict__ x,
                                                   float4* __restrict__ avg) {
    const int NU4 = U_N * D_N / 4;
    const int NT4 = N_N * D_N / 4;
    int i = blockIdx.x * blockDim.x + threadIdx.x;
    if (i >= NT4) return;
    float4 v = (i < NU4) ? ue[i] : ie[i - NU4];
    x[i] = v;
    float4 a;
    a.x = 0.25f * v.x; a.y = 0.25f * v.y; a.z = 0.25f * v.z; a.w = 0.25f * v.w;
    avg[i] = a;
}

// ------------- SpMM gather: one wave per row, fused avg axpy -------------
__global__ __launch_bounds__(256) void spmm_kernel(const float* __restrict__ x,
                                                   float* __restrict__ y,
                                                   float* __restrict__ avg,
                                                   const int* __restrict__ row_ptr,
                                                   const int* __restrict__ csr_dst,
                                                   const float* __restrict__ csr_w) {
    int wave = (int)((blockIdx.x * blockDim.x + threadIdx.x) >> 6);
    int lane = threadIdx.x & 63;
    if (wave >= N_N) return;
    int row = wave;
    int beg = row_ptr[row];
    int end = row_ptr[row + 1];
    int col = lane * 2;
    float2 acc = make_float2(0.0f, 0.0f);
    for (int k = beg; k < end; ++k) {
        int j = csr_dst[k];
        float wv = csr_w[k];
        const float2 xv = *(const float2*)(x + (size_t)j * D_N + col);
        acc.x += wv * xv.x;
        acc.y += wv * xv.y;
    }
    *(float2*)(y + (size_t)row * D_N + col) = acc;
    float2* ap = (float2*)(avg + (size_t)row * D_N + col);
    float2 a = *ap;
    a.x += 0.25f * acc.x;
    a.y += 0.25f * acc.y;
    *ap = a;
}

extern "C" void kernel_launch(void* const* d_in, const int* in_sizes, int n_in,
                              void* d_out, int out_size, void* d_ws, size_t ws_size,
                              hipStream_t stream) {
    const float* ue  = (const float*)d_in[0];
    const float* ie  = (const float*)d_in[1];
    const int* esrc  = (const int*)d_in[2];
    const int* edst  = (const int*)d_in[3];
    float* avg = (float*)d_out;
    const int E = in_sizes[2];
    const int N = N_N;

    // ---- workspace carve-up ----
    char* ws = (char*)d_ws;
    size_t off = 0;
    auto alloc = [&](size_t bytes) -> void* {
        void* p = (void*)(ws + off);
        off += bytes;
        off = (off + 255) & ~((size_t)255);
        return p;
    };
    float* x0       = (float*)alloc((size_t)N * D_N * sizeof(float));
    float* x1       = (float*)alloc((size_t)N * D_N * sizeof(float));
    int*   cnt      = (int*)  alloc((size_t)N * sizeof(int));
    int*   row_ptr  = (int*)  alloc((size_t)(N + 1) * sizeof(int));
    int*   fill_pos = (int*)  alloc((size_t)N * sizeof(int));
    float* dinv     = (float*)alloc((size_t)N * sizeof(float));
    int*   csr_dst  = (int*)  alloc((size_t)E * sizeof(int));
    float* csr_w    = (float*)alloc((size_t)E * sizeof(float));

    // ---- build CSR ----
    hipMemsetAsync(cnt, 0, (size_t)N * sizeof(int), stream);
    int eblocks = (E + 255) / 256;
    if (eblocks > 2048) eblocks = 2048;
    hist_kernel<<<eblocks, 256, 0, stream>>>(esrc, cnt, E);
    scan_kernel<<<1, 256, 0, stream>>>(cnt, row_ptr, fill_pos, dinv, N, E);
    scatter_kernel<<<eblocks, 256, 0, stream>>>(esrc, edst, fill_pos, dinv,
                                                csr_dst, csr_w, E);

    // ---- init x0 and avg = 0.25 * x0 ----
    const int NT4 = N * D_N / 4;
    init_kernel<<<(NT4 + 255) / 256, 256, 0, stream>>>(
        (const float4*)ue, (const float4*)ie, (float4*)x0, (float4*)avg);

    // ---- 3 propagation layers (ping-pong), fused avg += 0.25*y ----
    int sblocks = (N * 64 + 255) / 256;   // one wave (64 lanes) per row
    float* xc = x0;
    float* xn = x1;
    for (int layer = 0; layer < 3; ++layer) {
        spmm_kernel<<<sblocks, 256, 0, stream>>>(xc, xn, avg, row_ptr, csr_dst, csr_w);
        float* tmp = xc; xc = xn; xn = tmp;
    }
}

// Round 2
// 727.077 us; speedup vs baseline: 1.3898x; 1.3898x over previous
//
#include <hip/hip_runtime.h>

#define U_N 50000
#define I_N 25000
#define D_N 128
#define N_N (U_N + I_N)

#define SCAN_ELEMS_PER_BLOCK 1024                 // 256 threads x int4
#define NUM_SCAN_BLOCKS ((N_N + SCAN_ELEMS_PER_BLOCK - 1) / SCAN_ELEMS_PER_BLOCK)  // 74
#define N_PAD (NUM_SCAN_BLOCKS * SCAN_ELEMS_PER_BLOCK)                             // 75776

// ---------------- histogram: cnt[src[e]] += 1 ----------------
__global__ __launch_bounds__(256) void hist_kernel(const int* __restrict__ src,
                                                   int* __restrict__ cnt, int E) {
    int i = blockIdx.x * blockDim.x + threadIdx.x;
    int stride = gridDim.x * blockDim.x;
    for (; i < E; i += stride) {
        atomicAdd(&cnt[src[i]], 1);
    }
}

// -------- scan phase A: per-block sums (1024 elems / block) --------
__global__ __launch_bounds__(256) void block_sums_kernel(const int4* __restrict__ cnt4,
                                                         int* __restrict__ bsums) {
    int t = threadIdx.x;
    int idx = blockIdx.x * 256 + t;
    int4 v = cnt4[idx];
    int s = v.x + v.y + v.z + v.w;
    for (int off = 32; off; off >>= 1) s += __shfl_down(s, off);
    __shared__ int wsum[4];
    int wid = t >> 6, lane = t & 63;
    if (lane == 0) wsum[wid] = s;
    __syncthreads();
    if (t == 0) bsums[blockIdx.x] = wsum[0] + wsum[1] + wsum[2] + wsum[3];
}

// -------- scan phase B: scan the 74 block sums (one small block) --------
__global__ __launch_bounds__(128) void scan_bsums_kernel(const int* __restrict__ bsums,
                                                         int* __restrict__ boffs,
                                                         int nb, int* __restrict__ row_ptr,
                                                         int E, int N) {
    __shared__ int sd[128];
    int t = threadIdx.x;
    int v = (t < nb) ? bsums[t] : 0;
    sd[t] = v;
    __syncthreads();
    for (int off = 1; off < 128; off <<= 1) {
        int add = (t >= off) ? sd[t - off] : 0;
        __syncthreads();
        sd[t] += add;
        __syncthreads();
    }
    if (t < nb) boffs[t] = sd[t] - v;   // exclusive
    if (t == 0) row_ptr[N] = E;
}

// -------- scan phase C: local scan + writeback of row_ptr/fill_pos/dinv --------
__global__ __launch_bounds__(256) void local_scan_kernel(const int4* __restrict__ cnt4,
                                                         const int* __restrict__ boffs,
                                                         int* __restrict__ row_ptr,
                                                         int* __restrict__ fill_pos,
                                                         float* __restrict__ dinv, int N) {
    int t = threadIdx.x;
    int gidx = blockIdx.x * 256 + t;
    int4 v = cnt4[gidx];
    int p0 = v.x, p1 = p0 + v.y, p2 = p1 + v.z, p3 = p2 + v.w;   // thread-local inclusive
    int tsum = p3;
    int lane = t & 63, wid = t >> 6;
    int incl = tsum;
    for (int off = 1; off < 64; off <<= 1) {
        int u = __shfl_up(incl, off);
        if (lane >= off) incl += u;
    }
    int lexcl = incl - tsum;
    __shared__ int wsum[4];
    if (lane == 63) wsum[wid] = incl;
    __syncthreads();
    int woff = 0;
    for (int w = 0; w < wid; ++w) woff += wsum[w];
    int base = boffs[blockIdx.x] + woff + lexcl;
    int i0 = gidx * 4;
    int e0 = base, e1 = base + p0, e2 = base + p1, e3 = base + p2;
    if (i0 < N)     { row_ptr[i0]   = e0; fill_pos[i0]   = e0; dinv[i0]   = v.x > 0 ? rsqrtf((float)v.x) : 0.0f; }
    if (i0 + 1 < N) { row_ptr[i0+1] = e1; fill_pos[i0+1] = e1; dinv[i0+1] = v.y > 0 ? rsqrtf((float)v.y) : 0.0f; }
    if (i0 + 2 < N) { row_ptr[i0+2] = e2; fill_pos[i0+2] = e2; dinv[i0+2] = v.z > 0 ? rsqrtf((float)v.z) : 0.0f; }
    if (i0 + 3 < N) { row_ptr[i0+3] = e3; fill_pos[i0+3] = e3; dinv[i0+3] = v.w > 0 ? rsqrtf((float)v.w) : 0.0f; }
}

// ---------------- scatter edges into CSR order ----------------
__global__ __launch_bounds__(256) void scatter_kernel(const int* __restrict__ src,
                                                      const int* __restrict__ dst,
                                                      int* __restrict__ fill_pos,
                                                      const float* __restrict__ dinv,
                                                      int* __restrict__ csr_dst,
                                                      float* __restrict__ csr_w, int E) {
    int i = blockIdx.x * blockDim.x + threadIdx.x;
    int stride = gridDim.x * blockDim.x;
    for (; i < E; i += stride) {
        int s = src[i];
        int d = dst[i];
        int pos = atomicAdd(&fill_pos[s], 1);
        csr_dst[pos] = d;
        csr_w[pos] = dinv[s] * dinv[d];
    }
}

// ------------- init: x0 = concat(ue, ie); avg = 0.25*x0 -------------
__global__ __launch_bounds__(256) void init_kernel(const float4* __restrict__ ue,
                                                   const float4* __restrict__ ie,
                                                   float4* __restrict__ x,
                                                   float4* __restrict__ avg) {
    const int NU4 = U_N * D_N / 4;
    const int NT4 = N_N * D_N / 4;
    int i = blockIdx.x * blockDim.x + threadIdx.x;
    if (i >= NT4) return;
    float4 v = (i < NU4) ? ue[i] : ie[i - NU4];
    x[i] = v;
    float4 a;
    a.x = 0.25f * v.x; a.y = 0.25f * v.y; a.z = 0.25f * v.z; a.w = 0.25f * v.w;
    avg[i] = a;
}

// ------------- SpMM gather: one wave per row, fused avg axpy -------------
__global__ __launch_bounds__(256) void spmm_kernel(const float* __restrict__ x,
                                                   float* __restrict__ y,
                                                   float* __restrict__ avg,
                                                   const int* __restrict__ row_ptr,
                                                   const int* __restrict__ csr_dst,
                                                   const float* __restrict__ csr_w) {
    int wave = (int)((blockIdx.x * blockDim.x + threadIdx.x) >> 6);
    int lane = threadIdx.x & 63;
    if (wave >= N_N) return;
    int row = wave;
    int beg = row_ptr[row];
    int end = row_ptr[row + 1];
    int col = lane * 2;
    float2 acc = make_float2(0.0f, 0.0f);
    for (int k = beg; k < end; ++k) {
        int j = csr_dst[k];
        float wv = csr_w[k];
        const float2 xv = *(const float2*)(x + (size_t)j * D_N + col);
        acc.x += wv * xv.x;
        acc.y += wv * xv.y;
    }
    *(float2*)(y + (size_t)row * D_N + col) = acc;
    float2* ap = (float2*)(avg + (size_t)row * D_N + col);
    float2 a = *ap;
    a.x += 0.25f * acc.x;
    a.y += 0.25f * acc.y;
    *ap = a;
}

extern "C" void kernel_launch(void* const* d_in, const int* in_sizes, int n_in,
                              void* d_out, int out_size, void* d_ws, size_t ws_size,
                              hipStream_t stream) {
    const float* ue  = (const float*)d_in[0];
    const float* ie  = (const float*)d_in[1];
    const int* esrc  = (const int*)d_in[2];
    const int* edst  = (const int*)d_in[3];
    float* avg = (float*)d_out;
    const int E = in_sizes[2];
    const int N = N_N;

    // ---- workspace carve-up ----
    char* ws = (char*)d_ws;
    size_t off = 0;
    auto alloc = [&](size_t bytes) -> void* {
        void* p = (void*)(ws + off);
        off += bytes;
        off = (off + 255) & ~((size_t)255);
        return p;
    };
    float* x0       = (float*)alloc((size_t)N * D_N * sizeof(float));
    float* x1       = (float*)alloc((size_t)N * D_N * sizeof(float));
    int*   cnt      = (int*)  alloc((size_t)N_PAD * sizeof(int));      // padded for int4
    int*   row_ptr  = (int*)  alloc((size_t)(N + 1) * sizeof(int));
    int*   fill_pos = (int*)  alloc((size_t)N * sizeof(int));
    float* dinv     = (float*)alloc((size_t)N * sizeof(float));
    int*   bsums    = (int*)  alloc((size_t)NUM_SCAN_BLOCKS * sizeof(int));
    int*   boffs    = (int*)  alloc((size_t)NUM_SCAN_BLOCKS * sizeof(int));
    int*   csr_dst  = (int*)  alloc((size_t)E * sizeof(int));
    float* csr_w    = (float*)alloc((size_t)E * sizeof(float));

    // ---- build CSR ----
    hipMemsetAsync(cnt, 0, (size_t)N_PAD * sizeof(int), stream);
    int eblocks = (E + 255) / 256;
    if (eblocks > 2048) eblocks = 2048;
    hist_kernel<<<eblocks, 256, 0, stream>>>(esrc, cnt, E);
    block_sums_kernel<<<NUM_SCAN_BLOCKS, 256, 0, stream>>>((const int4*)cnt, bsums);
    scan_bsums_kernel<<<1, 128, 0, stream>>>(bsums, boffs, NUM_SCAN_BLOCKS, row_ptr, E, N);
    local_scan_kernel<<<NUM_SCAN_BLOCKS, 256, 0, stream>>>((const int4*)cnt, boffs,
                                                           row_ptr, fill_pos, dinv, N);
    scatter_kernel<<<eblocks, 256, 0, stream>>>(esrc, edst, fill_pos, dinv,
                                                csr_dst, csr_w, E);

    // ---- init x0 and avg = 0.25 * x0 ----
    const int NT4 = N * D_N / 4;
    init_kernel<<<(NT4 + 255) / 256, 256, 0, stream>>>(
        (const float4*)ue, (const float4*)ie, (float4*)x0, (float4*)avg);

    // ---- 3 propagation layers (ping-pong), fused avg += 0.25*y ----
    int sblocks = (N * 64 + 255) / 256;   // one wave (64 lanes) per row
    float* xc = x0;
    float* xn = x1;
    for (int layer = 0; layer < 3; ++layer) {
        spmm_kernel<<<sblocks, 256, 0, stream>>>(xc, xn, avg, row_ptr, csr_dst, csr_w);
        float* tmp = xc; xc = xn; xn = tmp;
    }
}

// Round 3
// 511.859 us; speedup vs baseline: 1.9741x; 1.4205x over previous
//
#include <hip/hip_runtime.h>

#define U_N 50000
#define I_N 25000
#define D_N 128
#define N_N (U_N + I_N)

#define SCAN_ELEMS_PER_BLOCK 1024                 // 256 threads x int4
#define NUM_SCAN_BLOCKS ((N_N + SCAN_ELEMS_PER_BLOCK - 1) / SCAN_ELEMS_PER_BLOCK)  // 74
#define N_PAD (NUM_SCAN_BLOCKS * SCAN_ELEMS_PER_BLOCK)                             // 75776

// ---------------- histogram: cnt[src[e]] += 1 ----------------
__global__ __launch_bounds__(256) void hist_kernel(const int* __restrict__ src,
                                                   int* __restrict__ cnt, int E) {
    int i = blockIdx.x * blockDim.x + threadIdx.x;
    int stride = gridDim.x * blockDim.x;
    for (; i < E; i += stride) {
        atomicAdd(&cnt[src[i]], 1);
    }
}

// -------- scan phase A: per-block sums (1024 elems / block) --------
__global__ __launch_bounds__(256) void block_sums_kernel(const int4* __restrict__ cnt4,
                                                         int* __restrict__ bsums) {
    int t = threadIdx.x;
    int idx = blockIdx.x * 256 + t;
    int4 v = cnt4[idx];
    int s = v.x + v.y + v.z + v.w;
    for (int off = 32; off; off >>= 1) s += __shfl_down(s, off);
    __shared__ int wsum[4];
    int wid = t >> 6, lane = t & 63;
    if (lane == 0) wsum[wid] = s;
    __syncthreads();
    if (t == 0) bsums[blockIdx.x] = wsum[0] + wsum[1] + wsum[2] + wsum[3];
}

// -------- scan phase B: scan the 74 block sums (one small block) --------
__global__ __launch_bounds__(128) void scan_bsums_kernel(const int* __restrict__ bsums,
                                                         int* __restrict__ boffs,
                                                         int nb, int* __restrict__ row_ptr,
                                                         int E, int N) {
    __shared__ int sd[128];
    int t = threadIdx.x;
    int v = (t < nb) ? bsums[t] : 0;
    sd[t] = v;
    __syncthreads();
    for (int off = 1; off < 128; off <<= 1) {
        int add = (t >= off) ? sd[t - off] : 0;
        __syncthreads();
        sd[t] += add;
        __syncthreads();
    }
    if (t < nb) boffs[t] = sd[t] - v;   // exclusive
    if (t == 0) row_ptr[N] = E;
}

// -------- scan phase C: local scan + writeback of row_ptr/fill_pos/dinv --------
__global__ __launch_bounds__(256) void local_scan_kernel(const int4* __restrict__ cnt4,
                                                         const int* __restrict__ boffs,
                                                         int* __restrict__ row_ptr,
                                                         int* __restrict__ fill_pos,
                                                         float* __restrict__ dinv, int N) {
    int t = threadIdx.x;
    int gidx = blockIdx.x * 256 + t;
    int4 v = cnt4[gidx];
    int p0 = v.x, p1 = p0 + v.y, p2 = p1 + v.z, p3 = p2 + v.w;   // thread-local inclusive
    int tsum = p3;
    int lane = t & 63, wid = t >> 6;
    int incl = tsum;
    for (int off = 1; off < 64; off <<= 1) {
        int u = __shfl_up(incl, off);
        if (lane >= off) incl += u;
    }
    int lexcl = incl - tsum;
    __shared__ int wsum[4];
    if (lane == 63) wsum[wid] = incl;
    __syncthreads();
    int woff = 0;
    for (int w = 0; w < wid; ++w) woff += wsum[w];
    int base = boffs[blockIdx.x] + woff + lexcl;
    int i0 = gidx * 4;
    int e0 = base, e1 = base + p0, e2 = base + p1, e3 = base + p2;
    if (i0 < N)     { row_ptr[i0]   = e0; fill_pos[i0]   = e0; dinv[i0]   = v.x > 0 ? rsqrtf((float)v.x) : 0.0f; }
    if (i0 + 1 < N) { row_ptr[i0+1] = e1; fill_pos[i0+1] = e1; dinv[i0+1] = v.y > 0 ? rsqrtf((float)v.y) : 0.0f; }
    if (i0 + 2 < N) { row_ptr[i0+2] = e2; fill_pos[i0+2] = e2; dinv[i0+2] = v.z > 0 ? rsqrtf((float)v.z) : 0.0f; }
    if (i0 + 3 < N) { row_ptr[i0+3] = e3; fill_pos[i0+3] = e3; dinv[i0+3] = v.w > 0 ? rsqrtf((float)v.w) : 0.0f; }
}

// ------ scatter edges into CSR order, (dst, w) interleaved as int2 ------
__global__ __launch_bounds__(256) void scatter_kernel(const int* __restrict__ src,
                                                      const int* __restrict__ dst,
                                                      int* __restrict__ fill_pos,
                                                      const float* __restrict__ dinv,
                                                      int2* __restrict__ csr_ew, int E) {
    int i = blockIdx.x * blockDim.x + threadIdx.x;
    int stride = gridDim.x * blockDim.x;
    for (; i < E; i += stride) {
        int s = src[i];
        int d = dst[i];
        int pos = atomicAdd(&fill_pos[s], 1);
        float w = dinv[s] * dinv[d];
        csr_ew[pos] = make_int2(d, __float_as_int(w));
    }
}

// ------------- init: x0 = concat(ue, ie); avg = 0.25*x0 -------------
__global__ __launch_bounds__(256) void init_kernel(const float4* __restrict__ ue,
                                                   const float4* __restrict__ ie,
                                                   float4* __restrict__ x,
                                                   float4* __restrict__ avg) {
    const int NU4 = U_N * D_N / 4;
    const int NT4 = N_N * D_N / 4;
    int i = blockIdx.x * blockDim.x + threadIdx.x;
    if (i >= NT4) return;
    float4 v = (i < NU4) ? ue[i] : ie[i - NU4];
    x[i] = v;
    float4 a;
    a.x = 0.25f * v.x; a.y = 0.25f * v.y; a.z = 0.25f * v.z; a.w = 0.25f * v.w;
    avg[i] = a;
}

// ------------- SpMM gather: one wave per row, 4x unrolled MLP -------------
// Grid is sized so wave id < N_N exactly (18750 blocks x 4 waves = 75000).
__global__ __launch_bounds__(256) void spmm_kernel(const float* __restrict__ x,
                                                   float* __restrict__ y,
                                                   float* __restrict__ avg,
                                                   const int* __restrict__ row_ptr,
                                                   const int2* __restrict__ csr_ew) {
    int row = (int)((blockIdx.x * blockDim.x + threadIdx.x) >> 6);
    int lane = threadIdx.x & 63;
    int beg = __builtin_amdgcn_readfirstlane(row_ptr[row]);
    int end = __builtin_amdgcn_readfirstlane(row_ptr[row + 1]);
    int col = lane * 2;
    const float* xc = x + col;
    float2 acc = make_float2(0.0f, 0.0f);
    int k = beg;
    // 4x unrolled main loop: 4 independent (idx,w) loads, then 4 independent
    // 512B row gathers in flight, then 8 FMAs. Sequential adds into one
    // accumulator keep summation order identical to the reference loop order.
    for (; k + 4 <= end; k += 4) {
        int2 e0 = csr_ew[k];
        int2 e1 = csr_ew[k + 1];
        int2 e2 = csr_ew[k + 2];
        int2 e3 = csr_ew[k + 3];
        float2 v0 = *(const float2*)(xc + (size_t)e0.x * D_N);
        float2 v1 = *(const float2*)(xc + (size_t)e1.x * D_N);
        float2 v2 = *(const float2*)(xc + (size_t)e2.x * D_N);
        float2 v3 = *(const float2*)(xc + (size_t)e3.x * D_N);
        float w0 = __int_as_float(e0.y);
        float w1 = __int_as_float(e1.y);
        float w2 = __int_as_float(e2.y);
        float w3 = __int_as_float(e3.y);
        acc.x += w0 * v0.x; acc.y += w0 * v0.y;
        acc.x += w1 * v1.x; acc.y += w1 * v1.y;
        acc.x += w2 * v2.x; acc.y += w2 * v2.y;
        acc.x += w3 * v3.x; acc.y += w3 * v3.y;
    }
    for (; k < end; ++k) {
        int2 e = csr_ew[k];
        float2 v = *(const float2*)(xc + (size_t)e.x * D_N);
        float w = __int_as_float(e.y);
        acc.x += w * v.x; acc.y += w * v.y;
    }
    *(float2*)(y + (size_t)row * D_N + col) = acc;
    float2* ap = (float2*)(avg + (size_t)row * D_N + col);
    float2 a = *ap;
    a.x += 0.25f * acc.x;
    a.y += 0.25f * acc.y;
    *ap = a;
}

extern "C" void kernel_launch(void* const* d_in, const int* in_sizes, int n_in,
                              void* d_out, int out_size, void* d_ws, size_t ws_size,
                              hipStream_t stream) {
    const float* ue  = (const float*)d_in[0];
    const float* ie  = (const float*)d_in[1];
    const int* esrc  = (const int*)d_in[2];
    const int* edst  = (const int*)d_in[3];
    float* avg = (float*)d_out;
    const int E = in_sizes[2];
    const int N = N_N;

    // ---- workspace carve-up ----
    char* ws = (char*)d_ws;
    size_t off = 0;
    auto alloc = [&](size_t bytes) -> void* {
        void* p = (void*)(ws + off);
        off += bytes;
        off = (off + 255) & ~((size_t)255);
        return p;
    };
    float* x0       = (float*)alloc((size_t)N * D_N * sizeof(float));
    float* x1       = (float*)alloc((size_t)N * D_N * sizeof(float));
    int*   cnt      = (int*)  alloc((size_t)N_PAD * sizeof(int));      // padded for int4
    int*   row_ptr  = (int*)  alloc((size_t)(N + 1) * sizeof(int));
    int*   fill_pos = (int*)  alloc((size_t)N * sizeof(int));
    float* dinv     = (float*)alloc((size_t)N * sizeof(float));
    int*   bsums    = (int*)  alloc((size_t)NUM_SCAN_BLOCKS * sizeof(int));
    int*   boffs    = (int*)  alloc((size_t)NUM_SCAN_BLOCKS * sizeof(int));
    int2*  csr_ew   = (int2*) alloc((size_t)E * sizeof(int2));

    // ---- build CSR ----
    hipMemsetAsync(cnt, 0, (size_t)N_PAD * sizeof(int), stream);
    int eblocks = (E + 255) / 256;
    if (eblocks > 2048) eblocks = 2048;
    hist_kernel<<<eblocks, 256, 0, stream>>>(esrc, cnt, E);
    block_sums_kernel<<<NUM_SCAN_BLOCKS, 256, 0, stream>>>((const int4*)cnt, bsums);
    scan_bsums_kernel<<<1, 128, 0, stream>>>(bsums, boffs, NUM_SCAN_BLOCKS, row_ptr, E, N);
    local_scan_kernel<<<NUM_SCAN_BLOCKS, 256, 0, stream>>>((const int4*)cnt, boffs,
                                                           row_ptr, fill_pos, dinv, N);
    scatter_kernel<<<eblocks, 256, 0, stream>>>(esrc, edst, fill_pos, dinv, csr_ew, E);

    // ---- init x0 and avg = 0.25 * x0 ----
    const int NT4 = N * D_N / 4;
    init_kernel<<<(NT4 + 255) / 256, 256, 0, stream>>>(
        (const float4*)ue, (const float4*)ie, (float4*)x0, (float4*)avg);

    // ---- 3 propagation layers (ping-pong), fused avg += 0.25*y ----
    int sblocks = (N * 64) / 256;   // 18750, exact: one wave per row
    float* xc = x0;
    float* xn = x1;
    for (int layer = 0; layer < 3; ++layer) {
        spmm_kernel<<<sblocks, 256, 0, stream>>>(xc, xn, avg, row_ptr, csr_ew);
        float* tmp = xc; xc = xn; xn = tmp;
    }
}

// Round 4
// 411.348 us; speedup vs baseline: 2.4565x; 1.2443x over previous
//
#include <hip/hip_runtime.h>
#include <hip/hip_fp16.h>

#define U_N 50000
#define I_N 25000
#define D_N 128
#define N_N (U_N + I_N)

#define SCAN_ELEMS_PER_BLOCK 1024                 // 256 threads x int4
#define NUM_SCAN_BLOCKS ((N_N + SCAN_ELEMS_PER_BLOCK - 1) / SCAN_ELEMS_PER_BLOCK)  // 74
#define N_PAD (NUM_SCAN_BLOCKS * SCAN_ELEMS_PER_BLOCK)                             // 75776

typedef float f4v __attribute__((ext_vector_type(4)));
typedef float f2v __attribute__((ext_vector_type(2)));
typedef unsigned int u2v __attribute__((ext_vector_type(2)));

// ---------------- histogram: cnt[src[e]] += 1 ----------------
__global__ __launch_bounds__(256) void hist_kernel(const int* __restrict__ src,
                                                   int* __restrict__ cnt, int E) {
    int i = blockIdx.x * blockDim.x + threadIdx.x;
    if (i < E) atomicAdd(&cnt[src[i]], 1);
}

// -------- scan phase A: per-block sums (1024 elems / block) --------
__global__ __launch_bounds__(256) void block_sums_kernel(const int4* __restrict__ cnt4,
                                                         int* __restrict__ bsums) {
    int t = threadIdx.x;
    int idx = blockIdx.x * 256 + t;
    int4 v = cnt4[idx];
    int s = v.x + v.y + v.z + v.w;
    for (int off = 32; off; off >>= 1) s += __shfl_down(s, off);
    __shared__ int wsum[4];
    int wid = t >> 6, lane = t & 63;
    if (lane == 0) wsum[wid] = s;
    __syncthreads();
    if (t == 0) bsums[blockIdx.x] = wsum[0] + wsum[1] + wsum[2] + wsum[3];
}

// -------- scan phase B: scan the 74 block sums (one small block) --------
__global__ __launch_bounds__(128) void scan_bsums_kernel(const int* __restrict__ bsums,
                                                         int* __restrict__ boffs,
                                                         int nb, int* __restrict__ row_ptr,
                                                         int E, int N) {
    __shared__ int sd[128];
    int t = threadIdx.x;
    int v = (t < nb) ? bsums[t] : 0;
    sd[t] = v;
    __syncthreads();
    for (int off = 1; off < 128; off <<= 1) {
        int add = (t >= off) ? sd[t - off] : 0;
        __syncthreads();
        sd[t] += add;
        __syncthreads();
    }
    if (t < nb) boffs[t] = sd[t] - v;   // exclusive
    if (t == 0) row_ptr[N] = E;
}

// -------- scan phase C: local scan + writeback of row_ptr/fill_pos/dinv --------
__global__ __launch_bounds__(256) void local_scan_kernel(const int4* __restrict__ cnt4,
                                                         const int* __restrict__ boffs,
                                                         int* __restrict__ row_ptr,
                                                         int* __restrict__ fill_pos,
                                                         float* __restrict__ dinv, int N) {
    int t = threadIdx.x;
    int gidx = blockIdx.x * 256 + t;
    int4 v = cnt4[gidx];
    int p0 = v.x, p1 = p0 + v.y, p2 = p1 + v.z, p3 = p2 + v.w;   // thread-local inclusive
    int tsum = p3;
    int lane = t & 63, wid = t >> 6;
    int incl = tsum;
    for (int off = 1; off < 64; off <<= 1) {
        int u = __shfl_up(incl, off);
        if (lane >= off) incl += u;
    }
    int lexcl = incl - tsum;
    __shared__ int wsum[4];
    if (lane == 63) wsum[wid] = incl;
    __syncthreads();
    int woff = 0;
    for (int w = 0; w < wid; ++w) woff += wsum[w];
    int base = boffs[blockIdx.x] + woff + lexcl;
    int i0 = gidx * 4;
    int e0 = base, e1 = base + p0, e2 = base + p1, e3 = base + p2;
    if (i0 < N)     { row_ptr[i0]   = e0; fill_pos[i0]   = e0; dinv[i0]   = v.x > 0 ? rsqrtf((float)v.x) : 0.0f; }
    if (i0 + 1 < N) { row_ptr[i0+1] = e1; fill_pos[i0+1] = e1; dinv[i0+1] = v.y > 0 ? rsqrtf((float)v.y) : 0.0f; }
    if (i0 + 2 < N) { row_ptr[i0+2] = e2; fill_pos[i0+2] = e2; dinv[i0+2] = v.z > 0 ? rsqrtf((float)v.z) : 0.0f; }
    if (i0 + 3 < N) { row_ptr[i0+3] = e3; fill_pos[i0+3] = e3; dinv[i0+3] = v.w > 0 ? rsqrtf((float)v.w) : 0.0f; }
}

// ------ scatter edges into CSR order: dst index only (4B/edge) ------
__global__ __launch_bounds__(256) void scatter_kernel(const int* __restrict__ src,
                                                      const int* __restrict__ dst,
                                                      int* __restrict__ fill_pos,
                                                      int* __restrict__ csr_dst, int E) {
    int i = blockIdx.x * blockDim.x + threadIdx.x;
    if (i >= E) return;
    int s = src[i];
    int d = dst[i];
    int pos = atomicAdd(&fill_pos[s], 1);
    __builtin_nontemporal_store(d, &csr_dst[pos]);
}

// -- init: x0' = dinv .* concat(ue,ie) in fp16 (prescaled); avg = 0.25*x --
__global__ __launch_bounds__(256) void init_kernel(const f4v* __restrict__ ue,
                                                   const f4v* __restrict__ ie,
                                                   const float* __restrict__ dinv,
                                                   __half2* __restrict__ x,
                                                   f4v* __restrict__ avg) {
    const int NU4 = U_N * D_N / 4;
    const int NT4 = N_N * D_N / 4;
    int i = blockIdx.x * blockDim.x + threadIdx.x;
    if (i >= NT4) return;
    f4v v = (i < NU4) ? ue[i] : ie[i - NU4];
    float di = dinv[i >> 5];            // 128 floats/row = 32 float4/row
    f4v a = v * 0.25f;
    __builtin_nontemporal_store(a, &avg[i]);
    __half2 h0 = __floats2half2_rn(di * v.x, di * v.y);
    __half2 h1 = __floats2half2_rn(di * v.z, di * v.w);
    u2v uu = { *(unsigned int*)&h0, *(unsigned int*)&h1 };
    __builtin_nontemporal_store(uu, (u2v*)(x + 2 * (size_t)i));
}

// ------- SpMM gather, weight-free (prescaled fp16 x), one wave/row -------
// y_i = dinv_i * sum_j x'_j ;  avg += 0.25*y ;  xnext' = dinv_i * y  (fp16)
__global__ __launch_bounds__(256) void spmm_kernel(const __half2* __restrict__ x,
                                                   __half2* __restrict__ xn,
                                                   float* __restrict__ avg,
                                                   const float* __restrict__ dinv,
                                                   const int* __restrict__ row_ptr,
                                                   const int* __restrict__ csr_dst) {
    int row = (int)((blockIdx.x * blockDim.x + threadIdx.x) >> 6);
    int lane = threadIdx.x & 63;
    int beg = __builtin_amdgcn_readfirstlane(row_ptr[row]);
    int end = __builtin_amdgcn_readfirstlane(row_ptr[row + 1]);
    float di = dinv[row];
    const __half2* xc = x + lane;       // row j lives at half2 offset j*64
    float accx = 0.0f, accy = 0.0f;
    int k = beg;
    for (; k + 8 <= end; k += 8) {
        int j[8];
        #pragma unroll
        for (int u = 0; u < 8; ++u) j[u] = csr_dst[k + u];
        #pragma unroll
        for (int u = 0; u < 8; ++u) {
            float2 f = __half22float2(xc[(size_t)j[u] * 64]);
            accx += f.x; accy += f.y;
        }
    }
    for (; k < end; ++k) {
        float2 f = __half22float2(xc[(size_t)csr_dst[k] * 64]);
        accx += f.x; accy += f.y;
    }
    float yx = di * accx, yy = di * accy;
    // avg += 0.25*y (nontemporal: keep L2 for the x gathers)
    float* ap = avg + (size_t)row * D_N + lane * 2;
    f2v a = __builtin_nontemporal_load((const f2v*)ap);
    a.x += 0.25f * yx;
    a.y += 0.25f * yy;
    __builtin_nontemporal_store(a, (f2v*)ap);
    // xnext' = dinv_i * y, fp16
    __half2 h = __floats2half2_rn(di * yx, di * yy);
    __builtin_nontemporal_store(*(unsigned int*)&h,
                                (unsigned int*)(xn + (size_t)row * 64 + lane));
}

extern "C" void kernel_launch(void* const* d_in, const int* in_sizes, int n_in,
                              void* d_out, int out_size, void* d_ws, size_t ws_size,
                              hipStream_t stream) {
    const float* ue  = (const float*)d_in[0];
    const float* ie  = (const float*)d_in[1];
    const int* esrc  = (const int*)d_in[2];
    const int* edst  = (const int*)d_in[3];
    float* avg = (float*)d_out;
    const int E = in_sizes[2];
    const int N = N_N;

    // ---- workspace carve-up ----
    char* ws = (char*)d_ws;
    size_t off = 0;
    auto alloc = [&](size_t bytes) -> void* {
        void* p = (void*)(ws + off);
        off += bytes;
        off = (off + 255) & ~((size_t)255);
        return p;
    };
    __half2* x0     = (__half2*)alloc((size_t)N * D_N * sizeof(__half));
    __half2* x1     = (__half2*)alloc((size_t)N * D_N * sizeof(__half));
    int*   cnt      = (int*)  alloc((size_t)N_PAD * sizeof(int));      // padded for int4
    int*   row_ptr  = (int*)  alloc((size_t)(N + 1) * sizeof(int));
    int*   fill_pos = (int*)  alloc((size_t)N * sizeof(int));
    float* dinv     = (float*)alloc((size_t)N * sizeof(float));
    int*   bsums    = (int*)  alloc((size_t)NUM_SCAN_BLOCKS * sizeof(int));
    int*   boffs    = (int*)  alloc((size_t)NUM_SCAN_BLOCKS * sizeof(int));
    int*   csr_dst  = (int*)  alloc((size_t)E * sizeof(int));

    // ---- build CSR + degrees ----
    hipMemsetAsync(cnt, 0, (size_t)N_PAD * sizeof(int), stream);
    int eblocks = (E + 255) / 256;    // 6250, exact coverage
    hist_kernel<<<eblocks, 256, 0, stream>>>(esrc, cnt, E);
    block_sums_kernel<<<NUM_SCAN_BLOCKS, 256, 0, stream>>>((const int4*)cnt, bsums);
    scan_bsums_kernel<<<1, 128, 0, stream>>>(bsums, boffs, NUM_SCAN_BLOCKS, row_ptr, E, N);
    local_scan_kernel<<<NUM_SCAN_BLOCKS, 256, 0, stream>>>((const int4*)cnt, boffs,
                                                           row_ptr, fill_pos, dinv, N);
    scatter_kernel<<<eblocks, 256, 0, stream>>>(esrc, edst, fill_pos, csr_dst, E);

    // ---- init x0' (prescaled fp16) and avg = 0.25 * x0 ----
    const int NT4 = N * D_N / 4;
    init_kernel<<<(NT4 + 255) / 256, 256, 0, stream>>>(
        (const f4v*)ue, (const f4v*)ie, dinv, x0, (f4v*)avg);

    // ---- 3 propagation layers (ping-pong), fused avg += 0.25*y ----
    int sblocks = (N * 64) / 256;   // 18750, exact: one wave per row
    __half2* xc = x0;
    __half2* xn = x1;
    for (int layer = 0; layer < 3; ++layer) {
        spmm_kernel<<<sblocks, 256, 0, stream>>>(xc, xn, avg, dinv, row_ptr, csr_dst);
        __half2* tmp = xc; xc = xn; xn = tmp;
    }
}

// Round 5
// 252.865 us; speedup vs baseline: 3.9960x; 1.6267x over previous
//
#include <hip/hip_runtime.h>
#include <hip/hip_fp16.h>

#define U_N 50000
#define I_N 25000
#define D_N 128
#define N_N (U_N + I_N)

#define ROWS_PER_B 256
#define NBUCK 293                       // ceil(75008/256); src>>8 in [0,292]
#define NBLK 256                        // partition blocks
#define SN (NBUCK * NBLK)               // 75008 scan elements

#define SCAN_ELEMS_PER_BLOCK 1024       // 256 threads x int4
#define NUM_SCAN_BLOCKS ((SN + SCAN_ELEMS_PER_BLOCK - 1) / SCAN_ELEMS_PER_BLOCK)  // 74
#define SN_PAD (NUM_SCAN_BLOCKS * SCAN_ELEMS_PER_BLOCK)                            // 75776

typedef float f4v __attribute__((ext_vector_type(4)));
typedef float f2v __attribute__((ext_vector_type(2)));
typedef unsigned int u2v __attribute__((ext_vector_type(2)));

// ---- Pass A: per-block coarse histogram (293 buckets) ----
__global__ __launch_bounds__(256) void part_hist_kernel(const int* __restrict__ src,
                                                        int* __restrict__ hist,
                                                        int E, int chunk) {
    __shared__ int h[NBUCK];
    int t = threadIdx.x;
    for (int i = t; i < NBUCK; i += 256) h[i] = 0;
    __syncthreads();
    int b = blockIdx.x;
    int s = b * chunk;
    int e = min(E, s + chunk);
    for (int i = s + t; i < e; i += 256)
        atomicAdd(&h[src[i] >> 8], 1);
    __syncthreads();
    for (int i = t; i < NBUCK; i += 256)
        hist[i * NBLK + b] = h[i];       // bucket-major layout for the scan
}

// -------- scan phase A: per-block sums (1024 elems / block) --------
__global__ __launch_bounds__(256) void block_sums_kernel(const int4* __restrict__ cnt4,
                                                         int* __restrict__ bsums) {
    int t = threadIdx.x;
    int idx = blockIdx.x * 256 + t;
    int4 v = cnt4[idx];
    int s = v.x + v.y + v.z + v.w;
    for (int off = 32; off; off >>= 1) s += __shfl_down(s, off);
    __shared__ int wsum[4];
    int wid = t >> 6, lane = t & 63;
    if (lane == 0) wsum[wid] = s;
    __syncthreads();
    if (t == 0) bsums[blockIdx.x] = wsum[0] + wsum[1] + wsum[2] + wsum[3];
}

// -------- scan phase B: scan the 74 block sums --------
__global__ __launch_bounds__(128) void scan_bsums_kernel(const int* __restrict__ bsums,
                                                         int* __restrict__ boffs, int nb) {
    __shared__ int sd[128];
    int t = threadIdx.x;
    int v = (t < nb) ? bsums[t] : 0;
    sd[t] = v;
    __syncthreads();
    for (int off = 1; off < 128; off <<= 1) {
        int add = (t >= off) ? sd[t - off] : 0;
        __syncthreads();
        sd[t] += add;
        __syncthreads();
    }
    if (t < nb) boffs[t] = sd[t] - v;   // exclusive
}

// -------- scan phase C: local scan + writeback of exclusive offsets --------
__global__ __launch_bounds__(256) void local_scan_offs_kernel(const int4* __restrict__ cnt4,
                                                              const int* __restrict__ boffs,
                                                              int4* __restrict__ offs4) {
    int t = threadIdx.x;
    int gidx = blockIdx.x * 256 + t;
    int4 v = cnt4[gidx];
    int p0 = v.x, p1 = p0 + v.y, p2 = p1 + v.z, p3 = p2 + v.w;
    int tsum = p3;
    int lane = t & 63, wid = t >> 6;
    int incl = tsum;
    for (int off = 1; off < 64; off <<= 1) {
        int u = __shfl_up(incl, off);
        if (lane >= off) incl += u;
    }
    int lexcl = incl - tsum;
    __shared__ int wsum[4];
    if (lane == 63) wsum[wid] = incl;
    __syncthreads();
    int woff = 0;
    for (int w = 0; w < wid; ++w) woff += wsum[w];
    int base = boffs[blockIdx.x] + woff + lexcl;
    int4 o;
    o.x = base; o.y = base + p0; o.z = base + p1; o.w = base + p2;
    offs4[gidx] = o;
}

// ---- Pass C: partition (src,dst) pairs into bucket-contiguous runs ----
__global__ __launch_bounds__(256) void partition_kernel(const int* __restrict__ src,
                                                        const int* __restrict__ dst,
                                                        const int* __restrict__ offs,
                                                        int2* __restrict__ part,
                                                        int E, int chunk) {
    __shared__ int c[NBUCK];
    int t = threadIdx.x;
    int b = blockIdx.x;
    for (int i = t; i < NBUCK; i += 256) c[i] = offs[i * NBLK + b];
    __syncthreads();
    int s = b * chunk;
    int e = min(E, s + chunk);
    for (int i = s + t; i < e; i += 256) {
        int sv = src[i];
        int dv = dst[i];
        int pos = atomicAdd(&c[sv >> 8], 1);
        part[pos] = make_int2(sv, dv);
    }
}

// ---- Pass D: per-bucket fine CSR build; writes row_ptr, dinv, csr_dst ----
__global__ __launch_bounds__(256) void bucket_csr_kernel(const int2* __restrict__ part,
                                                         const int* __restrict__ offs,
                                                         int* __restrict__ row_ptr,
                                                         float* __restrict__ dinv,
                                                         int* __restrict__ csr_dst, int E) {
    int B = blockIdx.x;                  // 0..292
    int t = threadIdx.x;
    int bstart = offs[B * NBLK];
    int bend = (B + 1 < NBUCK) ? offs[(B + 1) * NBLK] : E;
    __shared__ int cnt_s[ROWS_PER_B];
    __shared__ int base_s[ROWS_PER_B];
    __shared__ int wsum[4];
    cnt_s[t] = 0;
    __syncthreads();
    for (int i = bstart + t; i < bend; i += 256)
        atomicAdd(&cnt_s[part[i].x & 255], 1);
    __syncthreads();
    int v = cnt_s[t];
    int lane = t & 63, wid = t >> 6;
    int incl = v;
    for (int off = 1; off < 64; off <<= 1) {
        int u = __shfl_up(incl, off);
        if (lane >= off) incl += u;
    }
    if (lane == 63) wsum[wid] = incl;
    __syncthreads();
    int woff = 0;
    for (int w = 0; w < wid; ++w) woff += wsum[w];
    int excl = woff + incl - v;
    int gid = B * ROWS_PER_B + t;
    if (gid <= N_N) row_ptr[gid] = bstart + excl;   // row 75000 gets E naturally
    if (gid < N_N)  dinv[gid] = (v > 0) ? rsqrtf((float)v) : 0.0f;
    base_s[t] = bstart + excl;
    __syncthreads();
    cnt_s[t] = 0;                        // reuse as fill counters
    __syncthreads();
    for (int i = bstart + t; i < bend; i += 256) {
        int2 ev = part[i];
        int lr = ev.x & 255;
        int pos = base_s[lr] + atomicAdd(&cnt_s[lr], 1);
        csr_dst[pos] = ev.y;
    }
}

// -- init: x0' = dinv .* concat(ue,ie) in fp16 (prescaled); avg = 0.25*x --
__global__ __launch_bounds__(256) void init_kernel(const f4v* __restrict__ ue,
                                                   const f4v* __restrict__ ie,
                                                   const float* __restrict__ dinv,
                                                   __half2* __restrict__ x,
                                                   f4v* __restrict__ avg) {
    const int NU4 = U_N * D_N / 4;
    const int NT4 = N_N * D_N / 4;
    int i = blockIdx.x * blockDim.x + threadIdx.x;
    if (i >= NT4) return;
    f4v v = (i < NU4) ? ue[i] : ie[i - NU4];
    float di = dinv[i >> 5];            // 128 floats/row = 32 float4/row
    f4v a = v * 0.25f;
    __builtin_nontemporal_store(a, &avg[i]);
    __half2 h0 = __floats2half2_rn(di * v.x, di * v.y);
    __half2 h1 = __floats2half2_rn(di * v.z, di * v.w);
    u2v uu = { *(unsigned int*)&h0, *(unsigned int*)&h1 };
    __builtin_nontemporal_store(uu, (u2v*)(x + 2 * (size_t)i));
}

// ------- SpMM gather, weight-free (prescaled fp16 x), one wave/row -------
__global__ __launch_bounds__(256) void spmm_kernel(const __half2* __restrict__ x,
                                                   __half2* __restrict__ xn,
                                                   float* __restrict__ avg,
                                                   const float* __restrict__ dinv,
                                                   const int* __restrict__ row_ptr,
                                                   const int* __restrict__ csr_dst) {
    int row = (int)((blockIdx.x * blockDim.x + threadIdx.x) >> 6);
    int lane = threadIdx.x & 63;
    int beg = __builtin_amdgcn_readfirstlane(row_ptr[row]);
    int end = __builtin_amdgcn_readfirstlane(row_ptr[row + 1]);
    float di = dinv[row];
    const __half2* xc = x + lane;       // row j lives at half2 offset j*64
    float accx = 0.0f, accy = 0.0f;
    int k = beg;
    for (; k + 8 <= end; k += 8) {
        int j[8];
        #pragma unroll
        for (int u = 0; u < 8; ++u) j[u] = csr_dst[k + u];
        #pragma unroll
        for (int u = 0; u < 8; ++u) {
            float2 f = __half22float2(xc[(size_t)j[u] * 64]);
            accx += f.x; accy += f.y;
        }
    }
    for (; k < end; ++k) {
        float2 f = __half22float2(xc[(size_t)csr_dst[k] * 64]);
        accx += f.x; accy += f.y;
    }
    float yx = di * accx, yy = di * accy;
    float* ap = avg + (size_t)row * D_N + lane * 2;
    f2v a = __builtin_nontemporal_load((const f2v*)ap);
    a.x += 0.25f * yx;
    a.y += 0.25f * yy;
    __builtin_nontemporal_store(a, (f2v*)ap);
    __half2 h = __floats2half2_rn(di * yx, di * yy);
    __builtin_nontemporal_store(*(unsigned int*)&h,
                                (unsigned int*)(xn + (size_t)row * 64 + lane));
}

extern "C" void kernel_launch(void* const* d_in, const int* in_sizes, int n_in,
                              void* d_out, int out_size, void* d_ws, size_t ws_size,
                              hipStream_t stream) {
    const float* ue  = (const float*)d_in[0];
    const float* ie  = (const float*)d_in[1];
    const int* esrc  = (const int*)d_in[2];
    const int* edst  = (const int*)d_in[3];
    float* avg = (float*)d_out;
    const int E = in_sizes[2];
    const int N = N_N;

    // ---- workspace carve-up ----
    char* ws = (char*)d_ws;
    size_t off = 0;
    auto alloc = [&](size_t bytes) -> void* {
        void* p = (void*)(ws + off);
        off += bytes;
        off = (off + 255) & ~((size_t)255);
        return p;
    };
    __half2* x0     = (__half2*)alloc((size_t)N * D_N * sizeof(__half));
    __half2* x1     = (__half2*)alloc((size_t)N * D_N * sizeof(__half));
    int*   hist     = (int*)  alloc((size_t)SN_PAD * sizeof(int));
    int*   offs     = (int*)  alloc((size_t)SN_PAD * sizeof(int));
    int*   row_ptr  = (int*)  alloc((size_t)(N + 1) * sizeof(int));
    float* dinv     = (float*)alloc((size_t)N * sizeof(float));
    int*   bsums    = (int*)  alloc((size_t)NUM_SCAN_BLOCKS * sizeof(int));
    int*   boffs    = (int*)  alloc((size_t)NUM_SCAN_BLOCKS * sizeof(int));
    int2*  part     = (int2*) alloc((size_t)E * sizeof(int2));
    int*   csr_dst  = (int*)  alloc((size_t)E * sizeof(int));

    // ---- build CSR via two-level radix partition ----
    hipMemsetAsync(hist, 0, (size_t)SN_PAD * sizeof(int), stream);
    int chunk = (E + NBLK - 1) / NBLK;
    part_hist_kernel<<<NBLK, 256, 0, stream>>>(esrc, hist, E, chunk);
    block_sums_kernel<<<NUM_SCAN_BLOCKS, 256, 0, stream>>>((const int4*)hist, bsums);
    scan_bsums_kernel<<<1, 128, 0, stream>>>(bsums, boffs, NUM_SCAN_BLOCKS);
    local_scan_offs_kernel<<<NUM_SCAN_BLOCKS, 256, 0, stream>>>((const int4*)hist, boffs,
                                                                (int4*)offs);
    partition_kernel<<<NBLK, 256, 0, stream>>>(esrc, edst, offs, part, E, chunk);
    bucket_csr_kernel<<<NBUCK, 256, 0, stream>>>(part, offs, row_ptr, dinv, csr_dst, E);

    // ---- init x0' (prescaled fp16) and avg = 0.25 * x0 ----
    const int NT4 = N * D_N / 4;
    init_kernel<<<(NT4 + 255) / 256, 256, 0, stream>>>(
        (const f4v*)ue, (const f4v*)ie, dinv, x0, (f4v*)avg);

    // ---- 3 propagation layers (ping-pong), fused avg += 0.25*y ----
    int sblocks = (N * 64) / 256;   // 18750, exact: one wave per row
    __half2* xc = x0;
    __half2* xn = x1;
    for (int layer = 0; layer < 3; ++layer) {
        spmm_kernel<<<sblocks, 256, 0, stream>>>(xc, xn, avg, dinv, row_ptr, csr_dst);
        __half2* tmp = xc; xc = xn; xn = tmp;
    }
}

// Round 6
// 221.042 us; speedup vs baseline: 4.5713x; 1.1440x over previous
//
#include <hip/hip_runtime.h>
#include <hip/hip_fp16.h>

#define U_N 50000
#define I_N 25000
#define D_N 128
#define N_N (U_N + I_N)

#define ROWS_PER_B 256
#define NBUCK 293                       // ceil(75008/256); src>>8 in [0,292]
#define NBLK 256                        // partition blocks
#define SN (NBUCK * NBLK)               // 75008 scan elements

#define SCAN_ELEMS_PER_BLOCK 1024       // 256 threads x int4
#define NUM_SCAN_BLOCKS ((SN + SCAN_ELEMS_PER_BLOCK - 1) / SCAN_ELEMS_PER_BLOCK)  // 74
#define SN_PAD (NUM_SCAN_BLOCKS * SCAN_ELEMS_PER_BLOCK)                            // 75776

typedef float f4v __attribute__((ext_vector_type(4)));
typedef float f2v __attribute__((ext_vector_type(2)));
typedef unsigned int u2v __attribute__((ext_vector_type(2)));

// ---- Pass A: per-block coarse histogram (293 buckets) ----
__global__ __launch_bounds__(256) void part_hist_kernel(const int* __restrict__ src,
                                                        int* __restrict__ hist,
                                                        int E, int chunk) {
    __shared__ int h[NBUCK];
    int t = threadIdx.x;
    for (int i = t; i < NBUCK; i += 256) h[i] = 0;
    __syncthreads();
    int b = blockIdx.x;
    int s = b * chunk;
    int e = min(E, s + chunk);
    for (int i = s + t; i < e; i += 256)
        atomicAdd(&h[src[i] >> 8], 1);
    __syncthreads();
    for (int i = t; i < NBUCK; i += 256)
        hist[i * NBLK + b] = h[i];       // bucket-major layout for the scan
}

// -------- scan phase A: per-block sums (1024 elems / block) --------
__global__ __launch_bounds__(256) void block_sums_kernel(const int4* __restrict__ cnt4,
                                                         int* __restrict__ bsums) {
    int t = threadIdx.x;
    int idx = blockIdx.x * 256 + t;
    int4 v = cnt4[idx];
    int s = v.x + v.y + v.z + v.w;
    for (int off = 32; off; off >>= 1) s += __shfl_down(s, off);
    __shared__ int wsum[4];
    int wid = t >> 6, lane = t & 63;
    if (lane == 0) wsum[wid] = s;
    __syncthreads();
    if (t == 0) bsums[blockIdx.x] = wsum[0] + wsum[1] + wsum[2] + wsum[3];
}

// -------- scan phase B: scan the 74 block sums --------
__global__ __launch_bounds__(128) void scan_bsums_kernel(const int* __restrict__ bsums,
                                                         int* __restrict__ boffs, int nb) {
    __shared__ int sd[128];
    int t = threadIdx.x;
    int v = (t < nb) ? bsums[t] : 0;
    sd[t] = v;
    __syncthreads();
    for (int off = 1; off < 128; off <<= 1) {
        int add = (t >= off) ? sd[t - off] : 0;
        __syncthreads();
        sd[t] += add;
        __syncthreads();
    }
    if (t < nb) boffs[t] = sd[t] - v;   // exclusive
}

// -------- scan phase C: local scan + writeback of exclusive offsets --------
__global__ __launch_bounds__(256) void local_scan_offs_kernel(const int4* __restrict__ cnt4,
                                                              const int* __restrict__ boffs,
                                                              int4* __restrict__ offs4) {
    int t = threadIdx.x;
    int gidx = blockIdx.x * 256 + t;
    int4 v = cnt4[gidx];
    int p0 = v.x, p1 = p0 + v.y, p2 = p1 + v.z, p3 = p2 + v.w;
    int tsum = p3;
    int lane = t & 63, wid = t >> 6;
    int incl = tsum;
    for (int off = 1; off < 64; off <<= 1) {
        int u = __shfl_up(incl, off);
        if (lane >= off) incl += u;
    }
    int lexcl = incl - tsum;
    __shared__ int wsum[4];
    if (lane == 63) wsum[wid] = incl;
    __syncthreads();
    int woff = 0;
    for (int w = 0; w < wid; ++w) woff += wsum[w];
    int base = boffs[blockIdx.x] + woff + lexcl;
    int4 o;
    o.x = base; o.y = base + p0; o.z = base + p1; o.w = base + p2;
    offs4[gidx] = o;
}

// ---- Pass C: partition (src,dst) pairs into bucket-contiguous runs ----
__global__ __launch_bounds__(256) void partition_kernel(const int* __restrict__ src,
                                                        const int* __restrict__ dst,
                                                        const int* __restrict__ offs,
                                                        int2* __restrict__ part,
                                                        int E, int chunk) {
    __shared__ int c[NBUCK];
    int t = threadIdx.x;
    int b = blockIdx.x;
    for (int i = t; i < NBUCK; i += 256) c[i] = offs[i * NBLK + b];
    __syncthreads();
    int s = b * chunk;
    int e = min(E, s + chunk);
    for (int i = s + t; i < e; i += 256) {
        int sv = src[i];
        int dv = dst[i];
        int pos = atomicAdd(&c[sv >> 8], 1);
        part[pos] = make_int2(sv, dv);
    }
}

// ---- Pass D: per-bucket fine CSR build; writes row_ptr, dinv, csr_dst ----
__global__ __launch_bounds__(256) void bucket_csr_kernel(const int2* __restrict__ part,
                                                         const int* __restrict__ offs,
                                                         int* __restrict__ row_ptr,
                                                         float* __restrict__ dinv,
                                                         int* __restrict__ csr_dst, int E) {
    int B = blockIdx.x;                  // 0..292
    int t = threadIdx.x;
    int bstart = offs[B * NBLK];
    int bend = (B + 1 < NBUCK) ? offs[(B + 1) * NBLK] : E;
    __shared__ int cnt_s[ROWS_PER_B];
    __shared__ int base_s[ROWS_PER_B];
    __shared__ int wsum[4];
    cnt_s[t] = 0;
    __syncthreads();
    for (int i = bstart + t; i < bend; i += 256)
        atomicAdd(&cnt_s[part[i].x & 255], 1);
    __syncthreads();
    int v = cnt_s[t];
    int lane = t & 63, wid = t >> 6;
    int incl = v;
    for (int off = 1; off < 64; off <<= 1) {
        int u = __shfl_up(incl, off);
        if (lane >= off) incl += u;
    }
    if (lane == 63) wsum[wid] = incl;
    __syncthreads();
    int woff = 0;
    for (int w = 0; w < wid; ++w) woff += wsum[w];
    int excl = woff + incl - v;
    int gid = B * ROWS_PER_B + t;
    if (gid <= N_N) row_ptr[gid] = bstart + excl;   // row 75000 gets E naturally
    if (gid < N_N)  dinv[gid] = (v > 0) ? rsqrtf((float)v) : 0.0f;
    base_s[t] = bstart + excl;
    __syncthreads();
    cnt_s[t] = 0;                        // reuse as fill counters
    __syncthreads();
    for (int i = bstart + t; i < bend; i += 256) {
        int2 ev = part[i];
        int lr = ev.x & 255;
        int pos = base_s[lr] + atomicAdd(&cnt_s[lr], 1);
        csr_dst[pos] = ev.y;
    }
}

// -- init: x0' = dinv .* concat(ue,ie) in fp16 (prescaled). No avg write. --
// Plain (cache-resident) stores: layer 1 will gather these rows.
__global__ __launch_bounds__(256) void init_kernel(const f4v* __restrict__ ue,
                                                   const f4v* __restrict__ ie,
                                                   const float* __restrict__ dinv,
                                                   __half2* __restrict__ x) {
    const int NU4 = U_N * D_N / 4;
    const int NT4 = N_N * D_N / 4;
    int i = blockIdx.x * blockDim.x + threadIdx.x;
    if (i >= NT4) return;
    f4v v = (i < NU4) ? ue[i] : ie[i - NU4];
    float di = dinv[i >> 5];            // 128 floats/row = 32 float4/row
    __half2 h0 = __floats2half2_rn(di * v.x, di * v.y);
    __half2 h1 = __floats2half2_rn(di * v.z, di * v.w);
    u2v uu = { *(unsigned int*)&h0, *(unsigned int*)&h1 };
    *(u2v*)(x + 2 * (size_t)i) = uu;
}

// ------- mid SpMM: gather prescaled fp16 x, write xnext' only -------
// xnext'_i = dinv_i^2 * sum_j x'_j  (plain store: next layer re-gathers it)
__global__ __launch_bounds__(256) void spmm_mid_kernel(const __half2* __restrict__ x,
                                                       __half2* __restrict__ xn,
                                                       const float* __restrict__ dinv,
                                                       const int* __restrict__ row_ptr,
                                                       const int* __restrict__ csr_dst) {
    int row = (int)((blockIdx.x * blockDim.x + threadIdx.x) >> 6);
    int lane = threadIdx.x & 63;
    int beg = __builtin_amdgcn_readfirstlane(row_ptr[row]);
    int end = __builtin_amdgcn_readfirstlane(row_ptr[row + 1]);
    float di = dinv[row];
    const __half2* xc = x + lane;       // row j lives at half2 offset j*64
    float accx = 0.0f, accy = 0.0f;
    int k = beg;
    for (; k + 8 <= end; k += 8) {
        int j[8];
        #pragma unroll
        for (int u = 0; u < 8; ++u) j[u] = csr_dst[k + u];
        #pragma unroll
        for (int u = 0; u < 8; ++u) {
            float2 f = __half22float2(xc[(size_t)j[u] * 64]);
            accx += f.x; accy += f.y;
        }
    }
    for (; k < end; ++k) {
        float2 f = __half22float2(xc[(size_t)csr_dst[k] * 64]);
        accx += f.x; accy += f.y;
    }
    float s = di * di;
    __half2 h = __floats2half2_rn(s * accx, s * accy);
    *(unsigned int*)(xn + (size_t)row * 64 + lane) = *(unsigned int*)&h;
}

// ------- final SpMM: y3 + fused average -------
// avg = 0.25*(x0 + (x1' + x2')/dinv + y3),  y3 = dinv * sum_j x2'_j
__global__ __launch_bounds__(256) void spmm_final_kernel(const __half2* __restrict__ x2p,
                                                         const __half2* __restrict__ x1p,
                                                         const float* __restrict__ ue,
                                                         const float* __restrict__ ie,
                                                         float* __restrict__ avg,
                                                         const float* __restrict__ dinv,
                                                         const int* __restrict__ row_ptr,
                                                         const int* __restrict__ csr_dst) {
    int row = (int)((blockIdx.x * blockDim.x + threadIdx.x) >> 6);
    int lane = threadIdx.x & 63;
    int beg = __builtin_amdgcn_readfirstlane(row_ptr[row]);
    int end = __builtin_amdgcn_readfirstlane(row_ptr[row + 1]);
    float di = dinv[row];
    const __half2* xc = x2p + lane;
    float accx = 0.0f, accy = 0.0f;
    int k = beg;
    for (; k + 8 <= end; k += 8) {
        int j[8];
        #pragma unroll
        for (int u = 0; u < 8; ++u) j[u] = csr_dst[k + u];
        #pragma unroll
        for (int u = 0; u < 8; ++u) {
            float2 f = __half22float2(xc[(size_t)j[u] * 64]);
            accx += f.x; accy += f.y;
        }
    }
    for (; k < end; ++k) {
        float2 f = __half22float2(xc[(size_t)csr_dst[k] * 64]);
        accx += f.x; accy += f.y;
    }
    float y3x = di * accx, y3y = di * accy;
    float rs = (di > 0.0f) ? (1.0f / di) : 0.0f;
    const float* x0r = (row < U_N) ? (ue + (size_t)row * D_N)
                                   : (ie + (size_t)(row - U_N) * D_N);
    f2v v0 = *(const f2v*)(x0r + lane * 2);
    float2 f1 = __half22float2(x1p[(size_t)row * 64 + lane]);
    float2 f2_ = __half22float2(x2p[(size_t)row * 64 + lane]);
    f2v a;
    a.x = 0.25f * (v0.x + rs * (f1.x + f2_.x) + y3x);
    a.y = 0.25f * (v0.y + rs * (f1.y + f2_.y) + y3y);
    __builtin_nontemporal_store(a, (f2v*)(avg + (size_t)row * D_N + lane * 2));
}

extern "C" void kernel_launch(void* const* d_in, const int* in_sizes, int n_in,
                              void* d_out, int out_size, void* d_ws, size_t ws_size,
                              hipStream_t stream) {
    const float* ue  = (const float*)d_in[0];
    const float* ie  = (const float*)d_in[1];
    const int* esrc  = (const int*)d_in[2];
    const int* edst  = (const int*)d_in[3];
    float* avg = (float*)d_out;
    const int E = in_sizes[2];
    const int N = N_N;

    // ---- workspace carve-up ----
    char* ws = (char*)d_ws;
    size_t off = 0;
    auto alloc = [&](size_t bytes) -> void* {
        void* p = (void*)(ws + off);
        off += bytes;
        off = (off + 255) & ~((size_t)255);
        return p;
    };
    __half2* x0     = (__half2*)alloc((size_t)N * D_N * sizeof(__half));
    __half2* x1     = (__half2*)alloc((size_t)N * D_N * sizeof(__half));
    __half2* x2     = (__half2*)alloc((size_t)N * D_N * sizeof(__half));
    int*   hist     = (int*)  alloc((size_t)SN_PAD * sizeof(int));
    int*   offs     = (int*)  alloc((size_t)SN_PAD * sizeof(int));
    int*   row_ptr  = (int*)  alloc((size_t)(N + 1) * sizeof(int));
    float* dinv     = (float*)alloc((size_t)N * sizeof(float));
    int*   bsums    = (int*)  alloc((size_t)NUM_SCAN_BLOCKS * sizeof(int));
    int*   boffs    = (int*)  alloc((size_t)NUM_SCAN_BLOCKS * sizeof(int));
    int2*  part     = (int2*) alloc((size_t)E * sizeof(int2));
    int*   csr_dst  = (int*)  alloc((size_t)E * sizeof(int));

    // ---- build CSR via two-level radix partition ----
    hipMemsetAsync(hist, 0, (size_t)SN_PAD * sizeof(int), stream);
    int chunk = (E + NBLK - 1) / NBLK;
    part_hist_kernel<<<NBLK, 256, 0, stream>>>(esrc, hist, E, chunk);
    block_sums_kernel<<<NUM_SCAN_BLOCKS, 256, 0, stream>>>((const int4*)hist, bsums);
    scan_bsums_kernel<<<1, 128, 0, stream>>>(bsums, boffs, NUM_SCAN_BLOCKS);
    local_scan_offs_kernel<<<NUM_SCAN_BLOCKS, 256, 0, stream>>>((const int4*)hist, boffs,
                                                                (int4*)offs);
    partition_kernel<<<NBLK, 256, 0, stream>>>(esrc, edst, offs, part, E, chunk);
    bucket_csr_kernel<<<NBUCK, 256, 0, stream>>>(part, offs, row_ptr, dinv, csr_dst, E);

    // ---- init x0' (prescaled fp16) ----
    const int NT4 = N * D_N / 4;
    init_kernel<<<(NT4 + 255) / 256, 256, 0, stream>>>(
        (const f4v*)ue, (const f4v*)ie, dinv, x0);

    // ---- layers 1-2: pure propagate; layer 3: fused final average ----
    int sblocks = (N * 64) / 256;   // 18750, exact: one wave per row
    spmm_mid_kernel<<<sblocks, 256, 0, stream>>>(x0, x1, dinv, row_ptr, csr_dst);
    spmm_mid_kernel<<<sblocks, 256, 0, stream>>>(x1, x2, dinv, row_ptr, csr_dst);
    spmm_final_kernel<<<sblocks, 256, 0, stream>>>(x2, x1, ue, ie, avg, dinv,
                                                   row_ptr, csr_dst);
}

// Round 8
// 215.025 us; speedup vs baseline: 4.6993x; 1.0280x over previous
//
#include <hip/hip_runtime.h>
#include <hip/hip_fp16.h>

#define U_N 50000
#define I_N 25000
#define D_N 128
#define N_N (U_N + I_N)

#define ROWS_PER_B 256
#define NBUCK 293                       // ceil(75008/256); src>>8 in [0,292]
#define NBLK 256                        // partition blocks
#define SN (NBUCK * NBLK)               // 75008 scan elements

#define SCAN_ELEMS_PER_BLOCK 1024       // 256 threads x int4
#define NUM_SCAN_BLOCKS ((SN + SCAN_ELEMS_PER_BLOCK - 1) / SCAN_ELEMS_PER_BLOCK)  // 74
#define SN_PAD (NUM_SCAN_BLOCKS * SCAN_ELEMS_PER_BLOCK)                            // 75776

typedef float f4v __attribute__((ext_vector_type(4)));
typedef float f2v __attribute__((ext_vector_type(2)));
typedef unsigned int u2v __attribute__((ext_vector_type(2)));

// ---- Pass A: per-block coarse histogram (293 buckets) ----
__global__ __launch_bounds__(256) void part_hist_kernel(const int* __restrict__ src,
                                                        int* __restrict__ hist,
                                                        int E, int chunk) {
    __shared__ int h[NBUCK];
    int t = threadIdx.x;
    for (int i = t; i < NBUCK; i += 256) h[i] = 0;
    __syncthreads();
    int b = blockIdx.x;
    int s = b * chunk;
    int e = min(E, s + chunk);
    for (int i = s + t; i < e; i += 256)
        atomicAdd(&h[src[i] >> 8], 1);
    __syncthreads();
    for (int i = t; i < NBUCK; i += 256)
        hist[i * NBLK + b] = h[i];       // bucket-major layout for the scan
}

// -------- scan phase A: per-block sums (1024 elems / block) --------
__global__ __launch_bounds__(256) void block_sums_kernel(const int4* __restrict__ cnt4,
                                                         int* __restrict__ bsums) {
    int t = threadIdx.x;
    int idx = blockIdx.x * 256 + t;
    int4 v = cnt4[idx];
    int s = v.x + v.y + v.z + v.w;
    for (int off = 32; off; off >>= 1) s += __shfl_down(s, off);
    __shared__ int wsum[4];
    int wid = t >> 6, lane = t & 63;
    if (lane == 0) wsum[wid] = s;
    __syncthreads();
    if (t == 0) bsums[blockIdx.x] = wsum[0] + wsum[1] + wsum[2] + wsum[3];
}

// -------- scan phase B: scan the 74 block sums --------
__global__ __launch_bounds__(128) void scan_bsums_kernel(const int* __restrict__ bsums,
                                                         int* __restrict__ boffs, int nb) {
    __shared__ int sd[128];
    int t = threadIdx.x;
    int v = (t < nb) ? bsums[t] : 0;
    sd[t] = v;
    __syncthreads();
    for (int off = 1; off < 128; off <<= 1) {
        int add = (t >= off) ? sd[t - off] : 0;
        __syncthreads();
        sd[t] += add;
        __syncthreads();
    }
    if (t < nb) boffs[t] = sd[t] - v;   // exclusive
}

// -------- scan phase C: local scan + writeback of exclusive offsets --------
__global__ __launch_bounds__(256) void local_scan_offs_kernel(const int4* __restrict__ cnt4,
                                                              const int* __restrict__ boffs,
                                                              int4* __restrict__ offs4) {
    int t = threadIdx.x;
    int gidx = blockIdx.x * 256 + t;
    int4 v = cnt4[gidx];
    int p0 = v.x, p1 = p0 + v.y, p2 = p1 + v.z, p3 = p2 + v.w;
    int tsum = p3;
    int lane = t & 63, wid = t >> 6;
    int incl = tsum;
    for (int off = 1; off < 64; off <<= 1) {
        int u = __shfl_up(incl, off);
        if (lane >= off) incl += u;
    }
    int lexcl = incl - tsum;
    __shared__ int wsum[4];
    if (lane == 63) wsum[wid] = incl;
    __syncthreads();
    int woff = 0;
    for (int w = 0; w < wid; ++w) woff += wsum[w];
    int base = boffs[blockIdx.x] + woff + lexcl;
    int4 o;
    o.x = base; o.y = base + p0; o.z = base + p1; o.w = base + p2;
    offs4[gidx] = o;
}

// ---- Pass C: partition (src,dst) pairs into bucket-contiguous runs ----
__global__ __launch_bounds__(256) void partition_kernel(const int* __restrict__ src,
                                                        const int* __restrict__ dst,
                                                        const int* __restrict__ offs,
                                                        int2* __restrict__ part,
                                                        int E, int chunk) {
    __shared__ int c[NBUCK];
    int t = threadIdx.x;
    int b = blockIdx.x;
    for (int i = t; i < NBUCK; i += 256) c[i] = offs[i * NBLK + b];
    __syncthreads();
    int s = b * chunk;
    int e = min(E, s + chunk);
    for (int i = s + t; i < e; i += 256) {
        int sv = src[i];
        int dv = dst[i];
        int pos = atomicAdd(&c[sv >> 8], 1);
        part[pos] = make_int2(sv, dv);
    }
}

// ---- Pass D: per-bucket fine CSR build; writes row_ptr, dinv, csr_dst ----
__global__ __launch_bounds__(256) void bucket_csr_kernel(const int2* __restrict__ part,
                                                         const int* __restrict__ offs,
                                                         int* __restrict__ row_ptr,
                                                         float* __restrict__ dinv,
                                                         int* __restrict__ csr_dst, int E) {
    int B = blockIdx.x;                  // 0..292
    int t = threadIdx.x;
    int bstart = offs[B * NBLK];
    int bend = (B + 1 < NBUCK) ? offs[(B + 1) * NBLK] : E;
    __shared__ int cnt_s[ROWS_PER_B];
    __shared__ int base_s[ROWS_PER_B];
    __shared__ int wsum[4];
    cnt_s[t] = 0;
    __syncthreads();
    for (int i = bstart + t; i < bend; i += 256)
        atomicAdd(&cnt_s[part[i].x & 255], 1);
    __syncthreads();
    int v = cnt_s[t];
    int lane = t & 63, wid = t >> 6;
    int incl = v;
    for (int off = 1; off < 64; off <<= 1) {
        int u = __shfl_up(incl, off);
        if (lane >= off) incl += u;
    }
    if (lane == 63) wsum[wid] = incl;
    __syncthreads();
    int woff = 0;
    for (int w = 0; w < wid; ++w) woff += wsum[w];
    int excl = woff + incl - v;
    int gid = B * ROWS_PER_B + t;
    if (gid <= N_N) row_ptr[gid] = bstart + excl;   // row 75000 gets E naturally
    if (gid < N_N)  dinv[gid] = (v > 0) ? rsqrtf((float)v) : 0.0f;
    base_s[t] = bstart + excl;
    __syncthreads();
    cnt_s[t] = 0;                        // reuse as fill counters
    __syncthreads();
    for (int i = bstart + t; i < bend; i += 256) {
        int2 ev = part[i];
        int lr = ev.x & 255;
        int pos = base_s[lr] + atomicAdd(&cnt_s[lr], 1);
        csr_dst[pos] = ev.y;
    }
}

// -- init: x0' = dinv .* concat(ue,ie) in fp16 (prescaled). No avg write. --
__global__ __launch_bounds__(256) void init_kernel(const f4v* __restrict__ ue,
                                                   const f4v* __restrict__ ie,
                                                   const float* __restrict__ dinv,
                                                   __half2* __restrict__ x) {
    const int NU4 = U_N * D_N / 4;
    const int NT4 = N_N * D_N / 4;
    int i = blockIdx.x * blockDim.x + threadIdx.x;
    if (i >= NT4) return;
    f4v v = (i < NU4) ? ue[i] : ie[i - NU4];
    float di = dinv[i >> 5];            // 128 floats/row = 32 float4/row
    __half2 h0 = __floats2half2_rn(di * v.x, di * v.y);
    __half2 h1 = __floats2half2_rn(di * v.z, di * v.w);
    u2v uu = { *(unsigned int*)&h0, *(unsigned int*)&h1 };
    *(u2v*)(x + 2 * (size_t)i) = uu;
}

// ------- mid SpMM: one wave per row (R6 structure), unroll 16/8/1 -------
// xnext'_i = dinv_i^2 * sum_j x'_j
__global__ __launch_bounds__(256) void spmm_mid_kernel(const __half2* __restrict__ x,
                                                       __half2* __restrict__ xn,
                                                       const float* __restrict__ dinv,
                                                       const int* __restrict__ row_ptr,
                                                       const int* __restrict__ csr_dst) {
    int row = (int)((blockIdx.x * blockDim.x + threadIdx.x) >> 6);
    int lane = threadIdx.x & 63;
    int beg = __builtin_amdgcn_readfirstlane(row_ptr[row]);
    int end = __builtin_amdgcn_readfirstlane(row_ptr[row + 1]);
    float di = dinv[row];
    const __half2* xc = x + lane;       // row j lives at half2 offset j*64
    float accx = 0.0f, accy = 0.0f;
    int k = beg;
    for (; k + 16 <= end; k += 16) {
        int j[16];
        #pragma unroll
        for (int u = 0; u < 16; ++u) j[u] = csr_dst[k + u];
        #pragma unroll
        for (int u = 0; u < 16; ++u) {
            float2 f = __half22float2(xc[(size_t)j[u] * 64]);
            accx += f.x; accy += f.y;
        }
    }
    for (; k + 8 <= end; k += 8) {
        int j[8];
        #pragma unroll
        for (int u = 0; u < 8; ++u) j[u] = csr_dst[k + u];
        #pragma unroll
        for (int u = 0; u < 8; ++u) {
            float2 f = __half22float2(xc[(size_t)j[u] * 64]);
            accx += f.x; accy += f.y;
        }
    }
    for (; k < end; ++k) {
        float2 f = __half22float2(xc[(size_t)csr_dst[k] * 64]);
        accx += f.x; accy += f.y;
    }
    float s = di * di;
    __half2 h = __floats2half2_rn(s * accx, s * accy);
    *(unsigned int*)(xn + (size_t)row * 64 + lane) = __builtin_bit_cast(unsigned int, h);
}

// ------- final SpMM (R6 structure): y3 + fused average -------
// avg = 0.25*( (x0'+x1'+x2')/dinv + y3 ),  y3 = dinv * sum_j x2'_j
// deg-0 rows: avg = 0.25 * x0 read exactly from ue/ie.
__global__ __launch_bounds__(256) void spmm_final_kernel(const __half2* __restrict__ x2p,
                                                         const __half2* __restrict__ x1p,
                                                         const __half2* __restrict__ x0p,
                                                         const float* __restrict__ ue,
                                                         const float* __restrict__ ie,
                                                         float* __restrict__ avg,
                                                         const float* __restrict__ dinv,
                                                         const int* __restrict__ row_ptr,
                                                         const int* __restrict__ csr_dst) {
    int row = (int)((blockIdx.x * blockDim.x + threadIdx.x) >> 6);
    int lane = threadIdx.x & 63;
    int beg = __builtin_amdgcn_readfirstlane(row_ptr[row]);
    int end = __builtin_amdgcn_readfirstlane(row_ptr[row + 1]);
    float di = dinv[row];
    const __half2* xc = x2p + lane;
    float accx = 0.0f, accy = 0.0f;
    int k = beg;
    for (; k + 16 <= end; k += 16) {
        int j[16];
        #pragma unroll
        for (int u = 0; u < 16; ++u) j[u] = csr_dst[k + u];
        #pragma unroll
        for (int u = 0; u < 16; ++u) {
            float2 f = __half22float2(xc[(size_t)j[u] * 64]);
            accx += f.x; accy += f.y;
        }
    }
    for (; k + 8 <= end; k += 8) {
        int j[8];
        #pragma unroll
        for (int u = 0; u < 8; ++u) j[u] = csr_dst[k + u];
        #pragma unroll
        for (int u = 0; u < 8; ++u) {
            float2 f = __half22float2(xc[(size_t)j[u] * 64]);
            accx += f.x; accy += f.y;
        }
    }
    for (; k < end; ++k) {
        float2 f = __half22float2(xc[(size_t)csr_dst[k] * 64]);
        accx += f.x; accy += f.y;
    }
    f2v a;
    size_t ro = (size_t)row * 64 + lane;
    if (di > 0.0f) {
        float rs = 1.0f / di;
        float2 q0 = __half22float2(x0p[ro]);
        float2 q1 = __half22float2(x1p[ro]);
        float2 q2 = __half22float2(x2p[ro]);
        a.x = 0.25f * (rs * (q0.x + q1.x + q2.x) + di * accx);
        a.y = 0.25f * (rs * (q0.y + q1.y + q2.y) + di * accy);
    } else {
        const float* x0r = (row < U_N) ? (ue + (size_t)row * D_N)
                                       : (ie + (size_t)(row - U_N) * D_N);
        f2v v = *(const f2v*)(x0r + lane * 2);
        a.x = 0.25f * v.x;
        a.y = 0.25f * v.y;
    }
    __builtin_nontemporal_store(a, (f2v*)(avg + (size_t)row * D_N + lane * 2));
}

extern "C" void kernel_launch(void* const* d_in, const int* in_sizes, int n_in,
                              void* d_out, int out_size, void* d_ws, size_t ws_size,
                              hipStream_t stream) {
    const float* ue  = (const float*)d_in[0];
    const float* ie  = (const float*)d_in[1];
    const int* esrc  = (const int*)d_in[2];
    const int* edst  = (const int*)d_in[3];
    float* avg = (float*)d_out;
    const int E = in_sizes[2];
    const int N = N_N;

    // ---- workspace carve-up ----
    char* ws = (char*)d_ws;
    size_t off = 0;
    auto alloc = [&](size_t bytes) -> void* {
        void* p = (void*)(ws + off);
        off += bytes;
        off = (off + 255) & ~((size_t)255);
        return p;
    };
    __half2* x0     = (__half2*)alloc((size_t)N * D_N * sizeof(__half));
    __half2* x1     = (__half2*)alloc((size_t)N * D_N * sizeof(__half));
    __half2* x2     = (__half2*)alloc((size_t)N * D_N * sizeof(__half));
    int*   hist     = (int*)  alloc((size_t)SN_PAD * sizeof(int));
    int*   offs     = (int*)  alloc((size_t)SN_PAD * sizeof(int));
    int*   row_ptr  = (int*)  alloc((size_t)(N + 1) * sizeof(int));
    float* dinv     = (float*)alloc((size_t)N * sizeof(float));
    int*   bsums    = (int*)  alloc((size_t)NUM_SCAN_BLOCKS * sizeof(int));
    int*   boffs    = (int*)  alloc((size_t)NUM_SCAN_BLOCKS * sizeof(int));
    int2*  part     = (int2*) alloc((size_t)E * sizeof(int2));
    int*   csr_dst  = (int*)  alloc((size_t)E * sizeof(int));

    // ---- build CSR via two-level radix partition ----
    hipMemsetAsync(hist, 0, (size_t)SN_PAD * sizeof(int), stream);
    int chunk = (E + NBLK - 1) / NBLK;
    part_hist_kernel<<<NBLK, 256, 0, stream>>>(esrc, hist, E, chunk);
    block_sums_kernel<<<NUM_SCAN_BLOCKS, 256, 0, stream>>>((const int4*)hist, bsums);
    scan_bsums_kernel<<<1, 128, 0, stream>>>(bsums, boffs, NUM_SCAN_BLOCKS);
    local_scan_offs_kernel<<<NUM_SCAN_BLOCKS, 256, 0, stream>>>((const int4*)hist, boffs,
                                                                (int4*)offs);
    partition_kernel<<<NBLK, 256, 0, stream>>>(esrc, edst, offs, part, E, chunk);
    bucket_csr_kernel<<<NBUCK, 256, 0, stream>>>(part, offs, row_ptr, dinv, csr_dst, E);

    // ---- init x0' (prescaled fp16) ----
    const int NT4 = N * D_N / 4;
    init_kernel<<<(NT4 + 255) / 256, 256, 0, stream>>>(
        (const f4v*)ue, (const f4v*)ie, dinv, x0);

    // ---- layers: one wave per row (R6 structure) ----
    int sblocks = (N * 64) / 256;   // 18750, exact
    spmm_mid_kernel<<<sblocks, 256, 0, stream>>>(x0, x1, dinv, row_ptr, csr_dst);
    spmm_mid_kernel<<<sblocks, 256, 0, stream>>>(x1, x2, dinv, row_ptr, csr_dst);
    spmm_final_kernel<<<sblocks, 256, 0, stream>>>(x2, x1, x0, ue, ie, avg, dinv,
                                                   row_ptr, csr_dst);
}